// Round 11
// baseline (109.881 us; speedup 1.0000x reference)
//
#include <hip/hip_runtime.h>
#include <hip/hip_bf16.h>
#include <math.h>

typedef __attribute__((ext_vector_type(8))) short bf16x8;
typedef __attribute__((ext_vector_type(4))) short bf16x4;
typedef __attribute__((ext_vector_type(4))) float f32x4;

#define MFMA32 __builtin_amdgcn_mfma_f32_16x16x32_bf16
#define MFMA16 __builtin_amdgcn_mfma_f32_16x16x16bf16_1k

#define QSCALE 0.25503485964546277f  // (1/sqrt(32)) * log2(e)

__device__ inline short bfbits(float f) {
  union { float f; unsigned u; } v; v.f = f;
  unsigned r = v.u + 0x7fffu + ((v.u >> 16) & 1u);
  return (short)(r >> 16);
}
__device__ inline float bf2f(unsigned short u) {
  union { unsigned u; float f; } v; v.u = ((unsigned)u) << 16; return v.f;
}
__device__ inline void gll16(const void* g, void* l) {
  __builtin_amdgcn_global_load_lds(
      (const __attribute__((address_space(1))) unsigned*)g,
      (__attribute__((address_space(3))) unsigned*)l, 16, 0, 0);
}
// pack 4 f32 -> bf16x4 via v_cvt_pk_bf16_f32 (RTNE)
__device__ inline bf16x4 pk4(float e0, float e1, float e2, float e3) {
  unsigned lo, hi;
  asm("v_cvt_pk_bf16_f32 %0, %1, %2" : "=v"(lo) : "v"(e0), "v"(e1));
  asm("v_cvt_pk_bf16_f32 %0, %1, %2" : "=v"(hi) : "v"(e2), "v"(e3));
  union { unsigned u[2]; bf16x4 v; } cv;
  cv.u[0] = lo; cv.u[1] = hi;
  return cv.v;
}

// ---------------------------------------------------------------------------
// prep: one launch, three jobs (branch on blockIdx — uniform per block).
//   bid <  4096      : X f32 -> Xbf bf16 (8 elem/thread)
//   bid <  4096+256  : bias_bf[h][r][p] = bf16(sum_z pair[r,p,z]*bproj[z,h])
//   else (1280)      : Wt[col][k] (gate|qkv, q-cols pre-scaled), Woutt[col][k]
// ---------------------------------------------------------------------------
__global__ __launch_bounds__(256) void prep_kernel(
    const float* __restrict__ X, const float* __restrict__ pair,
    const float* __restrict__ bproj, const float* __restrict__ Wg,
    const float* __restrict__ Wqkv, const float* __restrict__ Wout,
    short* __restrict__ Xbf, short* __restrict__ bias_bf,
    short* __restrict__ Wt, short* __restrict__ Woutt) {
  int bid = blockIdx.x;
  int t = threadIdx.x;
  if (bid < 4096) {  // ---- xconv ----
    size_t i = ((size_t)bid * 256 + t) * 8;
    float4 a = *(const float4*)(X + i);
    float4 b = *(const float4*)(X + i + 4);
    bf16x8 o = {bfbits(a.x), bfbits(a.y), bfbits(a.z), bfbits(a.w),
                bfbits(b.x), bfbits(b.y), bfbits(b.z), bfbits(b.w)};
    *(bf16x8*)(Xbf + i) = o;
  } else if (bid < 4096 + 256) {  // ---- bias ----
    __shared__ float bp[128 * 8];
    for (int i = t; i < 128 * 8; i += 256) bp[i] = bproj[i];
    __syncthreads();
    int idx = (bid - 4096) * 256 + t;
    const float4* src = (const float4*)(pair + (size_t)idx * 128);
    float acc[8] = {};
#pragma unroll
    for (int z4 = 0; z4 < 32; ++z4) {
      float4 v = src[z4];
      const float* b0 = &bp[z4 * 32];
#pragma unroll
      for (int h = 0; h < 8; ++h) {
        acc[h] += v.x * b0[h] + v.y * b0[8 + h] +
                  v.z * b0[16 + h] + v.w * b0[24 + h];
      }
    }
#pragma unroll
    for (int h = 0; h < 8; ++h)
      bias_bf[(size_t)h * 65536 + idx] = bfbits(acc[h]);
  } else {  // ---- wconv ----
    int idx = (bid - 4352) * 256 + t;
    if (idx < 1024 * 256) {
      int col = idx >> 8, k = idx & 255;
      float v;
      if (col < 256) {
        v = Wg[k * 256 + col];
      } else {
        int wc = col - 256;
        v = Wqkv[k * 768 + wc];
        if ((wc % 96) < 32) v *= QSCALE;
      }
      Wt[idx] = bfbits(v);
    } else {
      int j = idx - 1024 * 256;
      int col = j >> 8, k = j & 255;
      Woutt[j] = bfbits(Wout[k * 256 + col]);
    }
  }
}

// ---------------------------------------------------------------------------
// gemm_fused3: Xbf[32768,256]bf16 @ Wt^T -> gate(sigmoid,bf16) | qkv(bf16)
// m97 structure: 2048 blocks (XCD-chunked, ny fastest), 256 thr (4 waves),
// tile 128x128, BK=32, both operands double-buffered via global_load_lds
// (inverse-swizzled source, linear dest, swizzled ds_read). LDS 32KB.
// ---------------------------------------------------------------------------
__global__ __launch_bounds__(256) void gemm_fused3(
    const short* __restrict__ Xbf, const short* __restrict__ Wt,
    short* __restrict__ gate_bf, short* __restrict__ qkv_bf) {
  __shared__ short As[2][128 * 32];  // 2 x 8KB
  __shared__ short Bs[2][128 * 32];  // 2 x 8KB
  int t = threadIdx.x;
  int lane = t & 63, wid = t >> 6;
  int lq = lane & 15, lg = lane >> 4;
  int wm = wid >> 1, wn = wid & 1;

  // XCD-chunk swizzle, n fastest: same m-panel's 8 n-tiles consecutive on
  // one XCD -> A-panel L2-resident after first block.
  int flat = blockIdx.x;
  int xcd = flat & 7, local = flat >> 3;
  int ny = local & 7;
  int bx = xcd * 32 + (local >> 3);
  int r0 = bx * 128;
  int cW = ny * 128;  // column base in the 1024-wide concat weight

  auto stageA = [&](int kq, int buf) {
#pragma unroll
    for (int c = 0; c < 2; ++c) {
      int D = c * 4096 + t * 16;   // linear LDS byte dest
      int row = D >> 6;
      int sl = ((D >> 4) & 3) ^ ((row >> 1) & 3);  // inverse-swizzled source
      gll16(Xbf + (size_t)(r0 + row) * 256 + kq * 32 + sl * 8,
            (char*)&As[buf][0] + D);
    }
  };
  auto stageB = [&](int kq, int buf) {
#pragma unroll
    for (int c = 0; c < 2; ++c) {
      int D = c * 4096 + t * 16;
      int col = D >> 6;
      int sl = ((D >> 4) & 3) ^ ((col >> 1) & 3);
      gll16(Wt + (size_t)(cW + col) * 256 + kq * 32 + sl * 8,
            (char*)&Bs[buf][0] + D);
    }
  };

  f32x4 acc[4][4];
#pragma unroll
  for (int a = 0; a < 4; ++a)
#pragma unroll
    for (int b = 0; b < 4; ++b) acc[a][b] = {0.f, 0.f, 0.f, 0.f};

  stageA(0, 0);
  stageB(0, 0);
  __syncthreads();

  for (int kq = 0; kq < 8; ++kq) {
    int buf = kq & 1;
    if (kq < 7) {
      stageA(kq + 1, buf ^ 1);
      stageB(kq + 1, buf ^ 1);
    }
    bf16x8 afr[4], bfr[4];
#pragma unroll
    for (int mf = 0; mf < 4; ++mf) {
      int row = wm * 64 + mf * 16 + lq;
      int sl = lg ^ ((row >> 1) & 3);
      afr[mf] = *(const bf16x8*)((const char*)&As[buf][0] + row * 64 + sl * 16);
    }
#pragma unroll
    for (int nf = 0; nf < 4; ++nf) {
      int col = wn * 64 + nf * 16 + lq;
      int sl = lg ^ ((col >> 1) & 3);
      bfr[nf] = *(const bf16x8*)((const char*)&Bs[buf][0] + col * 64 + sl * 16);
    }
#pragma unroll
    for (int mf = 0; mf < 4; ++mf)
#pragma unroll
      for (int nf = 0; nf < 4; ++nf)
        acc[mf][nf] = MFMA32(afr[mf], bfr[nf], acc[mf][nf], 0, 0, 0);
    __syncthreads();
  }

  if (cW < 256) {  // gate tiles (ny 0,1): sigmoid
#pragma unroll
    for (int mf = 0; mf < 4; ++mf)
#pragma unroll
      for (int nf = 0; nf < 4; ++nf) {
        int col = cW + wn * 64 + nf * 16 + lq;
#pragma unroll
        for (int j = 0; j < 4; ++j) {
          int row = r0 + wm * 64 + mf * 16 + lg * 4 + j;
          float v = acc[mf][nf][j];
          float sg = __builtin_amdgcn_rcpf(1.f + __expf(-v));
          gate_bf[(size_t)row * 256 + col] = bfbits(sg);
        }
      }
  } else {  // qkv tiles (ny 2..7)
    int cb = cW - 256;
#pragma unroll
    for (int mf = 0; mf < 4; ++mf)
#pragma unroll
      for (int nf = 0; nf < 4; ++nf) {
        int col = cb + wn * 64 + nf * 16 + lq;
#pragma unroll
        for (int j = 0; j < 4; ++j) {
          int row = r0 + wm * 64 + mf * 16 + lg * 4 + j;
          qkv_bf[(size_t)row * 768 + col] = bfbits(acc[mf][nf][j]);
        }
      }
  }
}

// ---------------------------------------------------------------------------
// attn v4: one block per (s,h), 512 thr (8 waves x 32 rows).
// K in LDS (gll16, slot-swizzled); V^T in LDS.
// simT = K@Q^T; E = exp2(simT) via v_exp + v_cvt_pk_bf16_f32;
// attend = (E@V)*rcp(E@1) + bias@V (bias@V via 16x16x32 MFMA);
// epilogue via LDS bounce, coalesced gate-mul + store.
// ---------------------------------------------------------------------------
__global__ __launch_bounds__(512, 4) void attn_mfma4(
    const short* __restrict__ qkv, const short* __restrict__ bias_bf,
    const short* __restrict__ gate_bf, short* __restrict__ attn_bf) {
  int s = blockIdx.x, h = blockIdx.y;
  __shared__ short Ks[8192];       // [256 p][4 slots of 16B], slot-swizzled
  __shared__ short Vt[32][260];    // V^T [c][p]
  short* Res = Ks;                 // reused after PV (barrier-protected)
  int t = threadIdx.x;
  int lane = t & 63, wid = t >> 6;
  int lq = lane & 15, lg = lane >> 4;
  const short* qkv_s = qkv + (size_t)s * 196608 + h * 96;

  // stage K: LDS linear dest, pre-swizzled global source (slot^((p>>1)&3))
#pragma unroll
  for (int q = 0; q < 2; ++q) {
    int off = wid * 2048 + q * 1024 + lane * 16;  // byte offset in Ks
    int p = off >> 6;
    int slot = (off >> 4) & 3;
    int cg = slot ^ ((p >> 1) & 3);
    gll16(qkv_s + p * 768 + 32 + cg * 8, (char*)Ks + wid * 2048 + q * 1024);
  }
  // stage V^T (register transpose)
  {
    int p = t >> 1, hf = t & 1;
    const short* src = qkv_s + p * 768 + 64 + hf * 16;
    bf16x8 v0 = *(const bf16x8*)src;
    bf16x8 v1 = *(const bf16x8*)(src + 8);
#pragma unroll
    for (int i = 0; i < 8; ++i) {
      Vt[hf * 16 + i][p] = v0[i];
      Vt[hf * 16 + 8 + i][p] = v1[i];
    }
  }

  int rbase = wid * 32;
  bf16x8 qf0 = *(const bf16x8*)(qkv_s + (size_t)(rbase + lq) * 768 + lg * 8);
  bf16x8 qf1 = *(const bf16x8*)(qkv_s + (size_t)(rbase + 16 + lq) * 768 + lg * 8);
  const short* bb0 =
      bias_bf + ((size_t)h * 256 + rbase + lq) * 256 + lg * 8;  // 16B frags
  const short* bb1 = bb0 + 16 * 256;

  f32x4 U[2][2], BV[2][2], L[2];
#pragma unroll
  for (int ri = 0; ri < 2; ++ri) {
    L[ri] = {0.f, 0.f, 0.f, 0.f};
#pragma unroll
    for (int ct = 0; ct < 2; ++ct) {
      U[ri][ct] = {0.f, 0.f, 0.f, 0.f};
      BV[ri][ct] = {0.f, 0.f, 0.f, 0.f};
    }
  }
  const bf16x4 ones = {16256, 16256, 16256, 16256};  // bf16 1.0

  __syncthreads();

#pragma unroll
  for (int qtr = 0; qtr < 4; ++qtr) {
    // K fragments (LDS) + bias fragments (global, 16B contiguous)
    bf16x8 kf[4];
    bf16x8 bfa[2][2];  // [chunk][ri]
#pragma unroll
    for (int i = 0; i < 4; ++i) {
      int row = (qtr * 4 + i) * 16 + lq;
      kf[i] = *(const bf16x8*)((const char*)Ks + row * 64 +
                               ((lg ^ ((row >> 1) & 3)) << 4));
    }
#pragma unroll
    for (int c2 = 0; c2 < 2; ++c2) {
      int chunk = qtr * 2 + c2;
      bfa[c2][0] = *(const bf16x8*)(bb0 + chunk * 32);
      bfa[c2][1] = *(const bf16x8*)(bb1 + chunk * 32);
    }

    // QK^T
    f32x4 acc[2][4];
#pragma unroll
    for (int ri = 0; ri < 2; ++ri)
#pragma unroll
      for (int i = 0; i < 4; ++i) acc[ri][i] = {0.f, 0.f, 0.f, 0.f};
    __builtin_amdgcn_s_setprio(1);
#pragma unroll
    for (int i = 0; i < 4; ++i) {
      acc[0][i] = MFMA32(kf[i], qf0, acc[0][i], 0, 0, 0);
      acc[1][i] = MFMA32(kf[i], qf1, acc[1][i], 0, 0, 0);
    }
    // bias@V (independent of QK/exp — fills MFMA pipe under the exp burst)
#pragma unroll
    for (int c2 = 0; c2 < 2; ++c2) {
      int chunk = qtr * 2 + c2;
      bf16x8 v0 = *(const bf16x8*)&Vt[lq][chunk * 32 + lg * 8];
      bf16x8 v1 = *(const bf16x8*)&Vt[16 + lq][chunk * 32 + lg * 8];
      BV[0][0] = MFMA32(bfa[c2][0], v0, BV[0][0], 0, 0, 0);
      BV[0][1] = MFMA32(bfa[c2][0], v1, BV[0][1], 0, 0, 0);
      BV[1][0] = MFMA32(bfa[c2][1], v0, BV[1][0], 0, 0, 0);
      BV[1][1] = MFMA32(bfa[c2][1], v1, BV[1][1], 0, 0, 0);
    }
    __builtin_amdgcn_s_setprio(0);

    // E = exp2(sim); pack to bf16 A-frags via v_cvt_pk
    bf16x4 af[2][4];
#pragma unroll
    for (int ri = 0; ri < 2; ++ri)
#pragma unroll
      for (int i = 0; i < 4; ++i)
        af[ri][i] = pk4(__builtin_amdgcn_exp2f(acc[ri][i][0]),
                        __builtin_amdgcn_exp2f(acc[ri][i][1]),
                        __builtin_amdgcn_exp2f(acc[ri][i][2]),
                        __builtin_amdgcn_exp2f(acc[ri][i][3]));

    // U = E@V, L = E@1
    __builtin_amdgcn_s_setprio(1);
#pragma unroll
    for (int i = 0; i < 4; ++i) {
      int kc = qtr * 4 + i;
      bf16x4 vf0 = *(const bf16x4*)&Vt[lq][kc * 16 + lg * 4];
      bf16x4 vf1 = *(const bf16x4*)&Vt[16 + lq][kc * 16 + lg * 4];
#pragma unroll
      for (int ri = 0; ri < 2; ++ri) {
        U[ri][0] = MFMA16(af[ri][i], vf0, U[ri][0], 0, 0, 0);
        U[ri][1] = MFMA16(af[ri][i], vf1, U[ri][1], 0, 0, 0);
        L[ri]    = MFMA16(af[ri][i], ones, L[ri], 0, 0, 0);
      }
    }
    __builtin_amdgcn_s_setprio(0);
  }

  __syncthreads();  // done reading Ks/Vt; reuse Ks as Res

  // results -> LDS bf16 [256 rows][32 cols]
#pragma unroll
  for (int ri = 0; ri < 2; ++ri) {
    f32x4 inv;
#pragma unroll
    for (int j = 0; j < 4; ++j) inv[j] = __builtin_amdgcn_rcpf(L[ri][j]);
#pragma unroll
    for (int ct = 0; ct < 2; ++ct) {
#pragma unroll
      for (int j = 0; j < 4; ++j) {
        int rl = rbase + ri * 16 + lg * 4 + j;
        Res[rl * 32 + ct * 16 + lq] =
            bfbits(U[ri][ct][j] * inv[j] + BV[ri][ct][j]);
      }
    }
  }
  __syncthreads();

  // coalesced epilogue: gate multiply + 16B stores
  {
    int row = t & 255, hf = t >> 8;
    size_t o = ((size_t)(s * 256 + row)) * 256 + h * 32 + hf * 16;
    bf16x8 r0 = *(const bf16x8*)&Res[row * 32 + hf * 16];
    bf16x8 r1 = *(const bf16x8*)&Res[row * 32 + hf * 16 + 8];
    bf16x8 g0 = *(const bf16x8*)&gate_bf[o];
    bf16x8 g1 = *(const bf16x8*)&gate_bf[o + 8];
    bf16x8 o0, o1;
#pragma unroll
    for (int i = 0; i < 8; ++i) {
      o0[i] = bfbits(bf2f((unsigned short)r0[i]) * bf2f((unsigned short)g0[i]));
      o1[i] = bfbits(bf2f((unsigned short)r1[i]) * bf2f((unsigned short)g1[i]));
    }
    *(bf16x8*)&attn_bf[o] = o0;
    *(bf16x8*)&attn_bf[o + 8] = o1;
  }
}

// ---------------------------------------------------------------------------
// gemm_out: attn_bf[32768,256] @ Woutt^T -> out f32
// ---------------------------------------------------------------------------
__global__ __launch_bounds__(256) void gemm_out2(
    const short* __restrict__ A, const short* __restrict__ Wt,
    float* __restrict__ out) {
  __shared__ short As2[2][128 * 64];
  __shared__ short Bs2[2][128 * 64];
  int t = threadIdx.x;
  int lane = t & 63, wid = t >> 6;
  int lq = lane & 15, lg = lane >> 4;
  int wm = wid >> 1, wn = wid & 1;
  int r0 = blockIdx.x * 128, n0 = blockIdx.y * 128;

  auto stage = [&](int s, int buf) {
#pragma unroll
    for (int q = 0; q < 4; ++q) {
      int P = wid * 4096 + q * 1024 + lane * 16;
      int row = P >> 7, kb = P & 127;
      int klog = kb ^ ((row & 7) << 4);
      gll16((const char*)A + ((size_t)(r0 + row) * 512 + s * 128 + klog),
            (char*)&As2[buf][0] + wid * 4096 + q * 1024);
      gll16((const char*)Wt + ((size_t)(n0 + row) * 512 + s * 128 + klog),
            (char*)&Bs2[buf][0] + wid * 4096 + q * 1024);
    }
  };

  f32x4 acc[4][4];
#pragma unroll
  for (int a = 0; a < 4; ++a)
#pragma unroll
    for (int b = 0; b < 4; ++b) acc[a][b] = {0.f, 0.f, 0.f, 0.f};

  stage(0, 0);
  __syncthreads();
  for (int s = 0; s < 4; ++s) {
    if (s < 3) stage(s + 1, (s + 1) & 1);
    bf16x8 afr[4][2], bfr[4][2];
#pragma unroll
    for (int kcl = 0; kcl < 2; ++kcl) {
#pragma unroll
      for (int mf = 0; mf < 4; ++mf) {
        int row = wm * 64 + mf * 16 + lq;
        int kb = (((kcl << 6) | (lg << 4))) ^ ((row & 7) << 4);
        afr[mf][kcl] = *(const bf16x8*)((const char*)&As2[s & 1][0] + row * 128 + kb);
      }
#pragma unroll
      for (int nf = 0; nf < 4; ++nf) {
        int col = wn * 64 + nf * 16 + lq;
        int kb = (((kcl << 6) | (lg << 4))) ^ ((col & 7) << 4);
        bfr[nf][kcl] = *(const bf16x8*)((const char*)&Bs2[s & 1][0] + col * 128 + kb);
      }
    }
#pragma unroll
    for (int mf = 0; mf < 4; ++mf)
#pragma unroll
      for (int nf = 0; nf < 4; ++nf)
#pragma unroll
        for (int kcl = 0; kcl < 2; ++kcl)
          acc[mf][nf] = MFMA32(afr[mf][kcl], bfr[nf][kcl], acc[mf][nf], 0, 0, 0);
    __syncthreads();
  }
#pragma unroll
  for (int mf = 0; mf < 4; ++mf)
#pragma unroll
    for (int nf = 0; nf < 4; ++nf) {
      int col = n0 + wn * 64 + nf * 16 + lq;
#pragma unroll
      for (int j = 0; j < 4; ++j) {
        int row = r0 + wm * 64 + mf * 16 + lg * 4 + j;
        out[(size_t)row * 256 + col] = acc[mf][nf][j];
      }
    }
}

// ---------------------------------------------------------------------------
extern "C" void kernel_launch(void* const* d_in, const int* in_sizes, int n_in,
                              void* d_out, int out_size, void* d_ws,
                              size_t ws_size, hipStream_t stream) {
  const float* msa  = (const float*)d_in[0];
  const float* pair = (const float*)d_in[1];
  const float* Wg   = (const float*)d_in[2];
  const float* Wqkv = (const float*)d_in[3];
  const float* Wout = (const float*)d_in[4];
  const float* Bp   = (const float*)d_in[5];
  float* out = (float*)d_out;
  short* sw = (short*)d_ws;

  short* bias_bf = sw;                 //   524288 shorts
  short* gate_bf = sw + 524288;        //  8388608
  short* qkv_bf  = sw + 8912896;       // 25165824
  short* attn_bf = sw + 34078720;      //  8388608
  short* Wt_bf   = sw + 42467328;      //   262144
  short* Woutt   = sw + 42729472;      //    65536
  short* X_bf    = sw + 42795008;      //  8388608

  hipLaunchKernelGGL(prep_kernel, dim3(5632), dim3(256), 0, stream,
                     msa, pair, Bp, Wg, Wqkv, Wout,
                     X_bf, bias_bf, Wt_bf, Woutt);
  hipLaunchKernelGGL(gemm_fused3, dim3(2048), dim3(256), 0, stream,
                     X_bf, Wt_bf, gate_bf, qkv_bf);
  hipLaunchKernelGGL(attn_mfma4, dim3(128, 8), dim3(512), 0, stream,
                     qkv_bf, bias_bf, gate_bf, attn_bf);
  hipLaunchKernelGGL(gemm_out2, dim3(256, 2), dim3(256), 0, stream,
                     attn_bf, Woutt, out);
}

// Round 12
// 102.020 us; speedup vs baseline: 1.0771x; 1.0771x over previous
//
#include <hip/hip_runtime.h>
#include <hip/hip_bf16.h>
#include <math.h>

typedef __attribute__((ext_vector_type(8))) short bf16x8;
typedef __attribute__((ext_vector_type(4))) short bf16x4;
typedef __attribute__((ext_vector_type(4))) float f32x4;

#define MFMA32 __builtin_amdgcn_mfma_f32_16x16x32_bf16
#define MFMA16 __builtin_amdgcn_mfma_f32_16x16x16bf16_1k

#define QSCALE 0.25503485964546277f  // (1/sqrt(32)) * log2(e)

__device__ inline short bfbits(float f) {
  union { float f; unsigned u; } v; v.f = f;
  unsigned r = v.u + 0x7fffu + ((v.u >> 16) & 1u);
  return (short)(r >> 16);
}
__device__ inline float bf2f(unsigned short u) {
  union { unsigned u; float f; } v; v.u = ((unsigned)u) << 16; return v.f;
}
__device__ inline void gll16(const void* g, void* l) {
  __builtin_amdgcn_global_load_lds(
      (const __attribute__((address_space(1))) unsigned*)g,
      (__attribute__((address_space(3))) unsigned*)l, 16, 0, 0);
}
// pack 4 f32 -> bf16x4 via v_cvt_pk_bf16_f32 (RTNE)
__device__ inline bf16x4 pk4(float e0, float e1, float e2, float e3) {
  unsigned lo, hi;
  asm("v_cvt_pk_bf16_f32 %0, %1, %2" : "=v"(lo) : "v"(e0), "v"(e1));
  asm("v_cvt_pk_bf16_f32 %0, %1, %2" : "=v"(hi) : "v"(e2), "v"(e3));
  union { unsigned u[2]; bf16x4 v; } cv;
  cv.u[0] = lo; cv.u[1] = hi;
  return cv.v;
}

// ---------------------------------------------------------------------------
// wconv: Wt[col][k] bf16 (gate | qkv w/ q-cols pre-scaled), Woutt[col][k],
// plus bprojT[h][z] f32 (transposed bias projection for bias2's s_loads).
// 1284 blocks.
// ---------------------------------------------------------------------------
__global__ __launch_bounds__(256) void wconv_kernel(
    const float* __restrict__ Wg, const float* __restrict__ Wqkv,
    const float* __restrict__ Wout, const float* __restrict__ bproj,
    short* __restrict__ Wt, short* __restrict__ Woutt,
    float* __restrict__ bprojT) {
  int idx = blockIdx.x * 256 + threadIdx.x;
  if (idx < 1024 * 256) {
    int col = idx >> 8, k = idx & 255;
    float v;
    if (col < 256) {
      v = Wg[k * 256 + col];
    } else {
      int wc = col - 256;
      v = Wqkv[k * 768 + wc];
      if ((wc % 96) < 32) v *= QSCALE;
    }
    Wt[idx] = bfbits(v);
  } else if (idx < 1024 * 256 + 256 * 256) {
    int j = idx - 1024 * 256;
    int col = j >> 8, k = j & 255;
    Woutt[j] = bfbits(Wout[k * 256 + col]);
  } else if (idx < 1024 * 256 + 256 * 256 + 1024) {
    int j = idx - (1024 * 256 + 256 * 256);
    int h = j >> 7, z = j & 127;
    bprojT[j] = bproj[z * 8 + h];
  }
}

// ---------------------------------------------------------------------------
// xconv: X f32 -> Xbf bf16 (pure stream, 4096 blocks)
// ---------------------------------------------------------------------------
__global__ __launch_bounds__(256) void xconv_kernel(
    const float* __restrict__ X, short* __restrict__ Xbf) {
  size_t i = ((size_t)blockIdx.x * 256 + threadIdx.x) * 8;
  float4 a = *(const float4*)(X + i);
  float4 b = *(const float4*)(X + i + 4);
  bf16x8 o = {bfbits(a.x), bfbits(a.y), bfbits(a.z), bfbits(a.w),
              bfbits(b.x), bfbits(b.y), bfbits(b.z), bfbits(b.w)};
  *(bf16x8*)(Xbf + i) = o;
}

// ---------------------------------------------------------------------------
// bias2: bias_bf[h][row] = bf16( sum_z pair[row,z] * bprojT[h,z] )
// 512 blocks x 256 thr. Wave-uniform z-half (readfirstlane -> SGPR) so the
// bprojT float4 loads scalarize to s_load; inner loop = pure v_fmac(v,s,v).
// Cross-half reduce via 4KB LDS.
// ---------------------------------------------------------------------------
__global__ __launch_bounds__(256) void bias2_kernel(
    const float* __restrict__ pair, const float* __restrict__ bprojT,
    short* __restrict__ bias_bf) {
  __shared__ float red[128][8];
  int t = threadIdx.x;
  int row = blockIdx.x * 128 + (t & 127);
  int zhalf = __builtin_amdgcn_readfirstlane(t >> 7);  // wave-uniform
  const float* src = pair + (size_t)row * 128 + zhalf * 64;
  const float* bT = bprojT + zhalf * 64;
  float acc[8] = {};
#pragma unroll
  for (int z4 = 0; z4 < 16; ++z4) {
    float4 v = ((const float4*)src)[z4];
#pragma unroll
    for (int h = 0; h < 8; ++h) {
      float4 b = *(const float4*)(bT + h * 128 + z4 * 4);  // s_load (uniform)
      acc[h] += v.x * b.x + v.y * b.y + v.z * b.z + v.w * b.w;
    }
  }
  if (t >= 128) {
#pragma unroll
    for (int h = 0; h < 8; ++h) red[t - 128][h] = acc[h];
  }
  __syncthreads();
  if (t < 128) {
#pragma unroll
    for (int h = 0; h < 8; ++h)
      bias_bf[(size_t)h * 65536 + row] = bfbits(acc[h] + red[t][h]);
  }
}

// ---------------------------------------------------------------------------
// gemm_fused3: Xbf[32768,256]bf16 @ Wt^T -> gate(sigmoid,bf16) | qkv(bf16)
// m97 structure: 2048 blocks (XCD-chunked, ny fastest), 256 thr (4 waves),
// tile 128x128, BK=32, both operands double-buffered via global_load_lds
// (inverse-swizzled source, linear dest, swizzled ds_read). LDS 32KB.
// ---------------------------------------------------------------------------
__global__ __launch_bounds__(256) void gemm_fused3(
    const short* __restrict__ Xbf, const short* __restrict__ Wt,
    short* __restrict__ gate_bf, short* __restrict__ qkv_bf) {
  __shared__ short As[2][128 * 32];  // 2 x 8KB
  __shared__ short Bs[2][128 * 32];  // 2 x 8KB
  int t = threadIdx.x;
  int lane = t & 63, wid = t >> 6;
  int lq = lane & 15, lg = lane >> 4;
  int wm = wid >> 1, wn = wid & 1;

  int flat = blockIdx.x;
  int xcd = flat & 7, local = flat >> 3;
  int ny = local & 7;
  int bx = xcd * 32 + (local >> 3);
  int r0 = bx * 128;
  int cW = ny * 128;

  auto stageA = [&](int kq, int buf) {
#pragma unroll
    for (int c = 0; c < 2; ++c) {
      int D = c * 4096 + t * 16;
      int row = D >> 6;
      int sl = ((D >> 4) & 3) ^ ((row >> 1) & 3);
      gll16(Xbf + (size_t)(r0 + row) * 256 + kq * 32 + sl * 8,
            (char*)&As[buf][0] + D);
    }
  };
  auto stageB = [&](int kq, int buf) {
#pragma unroll
    for (int c = 0; c < 2; ++c) {
      int D = c * 4096 + t * 16;
      int col = D >> 6;
      int sl = ((D >> 4) & 3) ^ ((col >> 1) & 3);
      gll16(Wt + (size_t)(cW + col) * 256 + kq * 32 + sl * 8,
            (char*)&Bs[buf][0] + D);
    }
  };

  f32x4 acc[4][4];
#pragma unroll
  for (int a = 0; a < 4; ++a)
#pragma unroll
    for (int b = 0; b < 4; ++b) acc[a][b] = {0.f, 0.f, 0.f, 0.f};

  stageA(0, 0);
  stageB(0, 0);
  __syncthreads();

  for (int kq = 0; kq < 8; ++kq) {
    int buf = kq & 1;
    if (kq < 7) {
      stageA(kq + 1, buf ^ 1);
      stageB(kq + 1, buf ^ 1);
    }
    bf16x8 afr[4], bfr[4];
#pragma unroll
    for (int mf = 0; mf < 4; ++mf) {
      int row = wm * 64 + mf * 16 + lq;
      int sl = lg ^ ((row >> 1) & 3);
      afr[mf] = *(const bf16x8*)((const char*)&As[buf][0] + row * 64 + sl * 16);
    }
#pragma unroll
    for (int nf = 0; nf < 4; ++nf) {
      int col = wn * 64 + nf * 16 + lq;
      int sl = lg ^ ((col >> 1) & 3);
      bfr[nf] = *(const bf16x8*)((const char*)&Bs[buf][0] + col * 64 + sl * 16);
    }
#pragma unroll
    for (int mf = 0; mf < 4; ++mf)
#pragma unroll
      for (int nf = 0; nf < 4; ++nf)
        acc[mf][nf] = MFMA32(afr[mf], bfr[nf], acc[mf][nf], 0, 0, 0);
    __syncthreads();
  }

  if (cW < 256) {
#pragma unroll
    for (int mf = 0; mf < 4; ++mf)
#pragma unroll
      for (int nf = 0; nf < 4; ++nf) {
        int col = cW + wn * 64 + nf * 16 + lq;
#pragma unroll
        for (int j = 0; j < 4; ++j) {
          int row = r0 + wm * 64 + mf * 16 + lg * 4 + j;
          float v = acc[mf][nf][j];
          float sg = __builtin_amdgcn_rcpf(1.f + __expf(-v));
          gate_bf[(size_t)row * 256 + col] = bfbits(sg);
        }
      }
  } else {
    int cb = cW - 256;
#pragma unroll
    for (int mf = 0; mf < 4; ++mf)
#pragma unroll
      for (int nf = 0; nf < 4; ++nf) {
        int col = cb + wn * 64 + nf * 16 + lq;
#pragma unroll
        for (int j = 0; j < 4; ++j) {
          int row = r0 + wm * 64 + mf * 16 + lg * 4 + j;
          qkv_bf[(size_t)row * 768 + col] = bfbits(acc[mf][nf][j]);
        }
      }
  }
}

// ---------------------------------------------------------------------------
// attn v4: one block per (s,h), 512 thr (8 waves x 32 rows).
// ---------------------------------------------------------------------------
__global__ __launch_bounds__(512, 4) void attn_mfma4(
    const short* __restrict__ qkv, const short* __restrict__ bias_bf,
    const short* __restrict__ gate_bf, short* __restrict__ attn_bf) {
  int s = blockIdx.x, h = blockIdx.y;
  __shared__ short Ks[8192];
  __shared__ short Vt[32][260];
  short* Res = Ks;
  int t = threadIdx.x;
  int lane = t & 63, wid = t >> 6;
  int lq = lane & 15, lg = lane >> 4;
  const short* qkv_s = qkv + (size_t)s * 196608 + h * 96;

#pragma unroll
  for (int q = 0; q < 2; ++q) {
    int off = wid * 2048 + q * 1024 + lane * 16;
    int p = off >> 6;
    int slot = (off >> 4) & 3;
    int cg = slot ^ ((p >> 1) & 3);
    gll16(qkv_s + p * 768 + 32 + cg * 8, (char*)Ks + wid * 2048 + q * 1024);
  }
  {
    int p = t >> 1, hf = t & 1;
    const short* src = qkv_s + p * 768 + 64 + hf * 16;
    bf16x8 v0 = *(const bf16x8*)src;
    bf16x8 v1 = *(const bf16x8*)(src + 8);
#pragma unroll
    for (int i = 0; i < 8; ++i) {
      Vt[hf * 16 + i][p] = v0[i];
      Vt[hf * 16 + 8 + i][p] = v1[i];
    }
  }

  int rbase = wid * 32;
  bf16x8 qf0 = *(const bf16x8*)(qkv_s + (size_t)(rbase + lq) * 768 + lg * 8);
  bf16x8 qf1 = *(const bf16x8*)(qkv_s + (size_t)(rbase + 16 + lq) * 768 + lg * 8);
  const short* bb0 =
      bias_bf + ((size_t)h * 256 + rbase + lq) * 256 + lg * 8;
  const short* bb1 = bb0 + 16 * 256;

  f32x4 U[2][2], BV[2][2], L[2];
#pragma unroll
  for (int ri = 0; ri < 2; ++ri) {
    L[ri] = {0.f, 0.f, 0.f, 0.f};
#pragma unroll
    for (int ct = 0; ct < 2; ++ct) {
      U[ri][ct] = {0.f, 0.f, 0.f, 0.f};
      BV[ri][ct] = {0.f, 0.f, 0.f, 0.f};
    }
  }
  const bf16x4 ones = {16256, 16256, 16256, 16256};

  __syncthreads();

#pragma unroll
  for (int qtr = 0; qtr < 4; ++qtr) {
    bf16x8 kf[4];
    bf16x8 bfa[2][2];
#pragma unroll
    for (int i = 0; i < 4; ++i) {
      int row = (qtr * 4 + i) * 16 + lq;
      kf[i] = *(const bf16x8*)((const char*)Ks + row * 64 +
                               ((lg ^ ((row >> 1) & 3)) << 4));
    }
#pragma unroll
    for (int c2 = 0; c2 < 2; ++c2) {
      int chunk = qtr * 2 + c2;
      bfa[c2][0] = *(const bf16x8*)(bb0 + chunk * 32);
      bfa[c2][1] = *(const bf16x8*)(bb1 + chunk * 32);
    }

    f32x4 acc[2][4];
#pragma unroll
    for (int ri = 0; ri < 2; ++ri)
#pragma unroll
      for (int i = 0; i < 4; ++i) acc[ri][i] = {0.f, 0.f, 0.f, 0.f};
    __builtin_amdgcn_s_setprio(1);
#pragma unroll
    for (int i = 0; i < 4; ++i) {
      acc[0][i] = MFMA32(kf[i], qf0, acc[0][i], 0, 0, 0);
      acc[1][i] = MFMA32(kf[i], qf1, acc[1][i], 0, 0, 0);
    }
#pragma unroll
    for (int c2 = 0; c2 < 2; ++c2) {
      int chunk = qtr * 2 + c2;
      bf16x8 v0 = *(const bf16x8*)&Vt[lq][chunk * 32 + lg * 8];
      bf16x8 v1 = *(const bf16x8*)&Vt[16 + lq][chunk * 32 + lg * 8];
      BV[0][0] = MFMA32(bfa[c2][0], v0, BV[0][0], 0, 0, 0);
      BV[0][1] = MFMA32(bfa[c2][0], v1, BV[0][1], 0, 0, 0);
      BV[1][0] = MFMA32(bfa[c2][1], v0, BV[1][0], 0, 0, 0);
      BV[1][1] = MFMA32(bfa[c2][1], v1, BV[1][1], 0, 0, 0);
    }
    __builtin_amdgcn_s_setprio(0);

    bf16x4 af[2][4];
#pragma unroll
    for (int ri = 0; ri < 2; ++ri)
#pragma unroll
      for (int i = 0; i < 4; ++i)
        af[ri][i] = pk4(__builtin_amdgcn_exp2f(acc[ri][i][0]),
                        __builtin_amdgcn_exp2f(acc[ri][i][1]),
                        __builtin_amdgcn_exp2f(acc[ri][i][2]),
                        __builtin_amdgcn_exp2f(acc[ri][i][3]));

    __builtin_amdgcn_s_setprio(1);
#pragma unroll
    for (int i = 0; i < 4; ++i) {
      int kc = qtr * 4 + i;
      bf16x4 vf0 = *(const bf16x4*)&Vt[lq][kc * 16 + lg * 4];
      bf16x4 vf1 = *(const bf16x4*)&Vt[16 + lq][kc * 16 + lg * 4];
#pragma unroll
      for (int ri = 0; ri < 2; ++ri) {
        U[ri][0] = MFMA16(af[ri][i], vf0, U[ri][0], 0, 0, 0);
        U[ri][1] = MFMA16(af[ri][i], vf1, U[ri][1], 0, 0, 0);
        L[ri]    = MFMA16(af[ri][i], ones, L[ri], 0, 0, 0);
      }
    }
    __builtin_amdgcn_s_setprio(0);
  }

  __syncthreads();

#pragma unroll
  for (int ri = 0; ri < 2; ++ri) {
    f32x4 inv;
#pragma unroll
    for (int j = 0; j < 4; ++j) inv[j] = __builtin_amdgcn_rcpf(L[ri][j]);
#pragma unroll
    for (int ct = 0; ct < 2; ++ct) {
#pragma unroll
      for (int j = 0; j < 4; ++j) {
        int rl = rbase + ri * 16 + lg * 4 + j;
        Res[rl * 32 + ct * 16 + lq] =
            bfbits(U[ri][ct][j] * inv[j] + BV[ri][ct][j]);
      }
    }
  }
  __syncthreads();

  {
    int row = t & 255, hf = t >> 8;
    size_t o = ((size_t)(s * 256 + row)) * 256 + h * 32 + hf * 16;
    bf16x8 r0 = *(const bf16x8*)&Res[row * 32 + hf * 16];
    bf16x8 r1 = *(const bf16x8*)&Res[row * 32 + hf * 16 + 8];
    bf16x8 g0 = *(const bf16x8*)&gate_bf[o];
    bf16x8 g1 = *(const bf16x8*)&gate_bf[o + 8];
    bf16x8 o0, o1;
#pragma unroll
    for (int i = 0; i < 8; ++i) {
      o0[i] = bfbits(bf2f((unsigned short)r0[i]) * bf2f((unsigned short)g0[i]));
      o1[i] = bfbits(bf2f((unsigned short)r1[i]) * bf2f((unsigned short)g1[i]));
    }
    *(bf16x8*)&attn_bf[o] = o0;
    *(bf16x8*)&attn_bf[o + 8] = o1;
  }
}

// ---------------------------------------------------------------------------
// gemm_out: attn_bf[32768,256] @ Woutt^T -> out f32
// ---------------------------------------------------------------------------
__global__ __launch_bounds__(256) void gemm_out2(
    const short* __restrict__ A, const short* __restrict__ Wt,
    float* __restrict__ out) {
  __shared__ short As2[2][128 * 64];
  __shared__ short Bs2[2][128 * 64];
  int t = threadIdx.x;
  int lane = t & 63, wid = t >> 6;
  int lq = lane & 15, lg = lane >> 4;
  int wm = wid >> 1, wn = wid & 1;
  int r0 = blockIdx.x * 128, n0 = blockIdx.y * 128;

  auto stage = [&](int s, int buf) {
#pragma unroll
    for (int q = 0; q < 4; ++q) {
      int P = wid * 4096 + q * 1024 + lane * 16;
      int row = P >> 7, kb = P & 127;
      int klog = kb ^ ((row & 7) << 4);
      gll16((const char*)A + ((size_t)(r0 + row) * 512 + s * 128 + klog),
            (char*)&As2[buf][0] + wid * 4096 + q * 1024);
      gll16((const char*)Wt + ((size_t)(n0 + row) * 512 + s * 128 + klog),
            (char*)&Bs2[buf][0] + wid * 4096 + q * 1024);
    }
  };

  f32x4 acc[4][4];
#pragma unroll
  for (int a = 0; a < 4; ++a)
#pragma unroll
    for (int b = 0; b < 4; ++b) acc[a][b] = {0.f, 0.f, 0.f, 0.f};

  stage(0, 0);
  __syncthreads();
  for (int s = 0; s < 4; ++s) {
    if (s < 3) stage(s + 1, (s + 1) & 1);
    bf16x8 afr[4][2], bfr[4][2];
#pragma unroll
    for (int kcl = 0; kcl < 2; ++kcl) {
#pragma unroll
      for (int mf = 0; mf < 4; ++mf) {
        int row = wm * 64 + mf * 16 + lq;
        int kb = (((kcl << 6) | (lg << 4))) ^ ((row & 7) << 4);
        afr[mf][kcl] = *(const bf16x8*)((const char*)&As2[s & 1][0] + row * 128 + kb);
      }
#pragma unroll
      for (int nf = 0; nf < 4; ++nf) {
        int col = wn * 64 + nf * 16 + lq;
        int kb = (((kcl << 6) | (lg << 4))) ^ ((col & 7) << 4);
        bfr[nf][kcl] = *(const bf16x8*)((const char*)&Bs2[s & 1][0] + col * 128 + kb);
      }
    }
#pragma unroll
    for (int mf = 0; mf < 4; ++mf)
#pragma unroll
      for (int nf = 0; nf < 4; ++nf)
#pragma unroll
        for (int kcl = 0; kcl < 2; ++kcl)
          acc[mf][nf] = MFMA32(afr[mf][kcl], bfr[nf][kcl], acc[mf][nf], 0, 0, 0);
    __syncthreads();
  }
#pragma unroll
  for (int mf = 0; mf < 4; ++mf)
#pragma unroll
    for (int nf = 0; nf < 4; ++nf) {
      int col = n0 + wn * 64 + nf * 16 + lq;
#pragma unroll
      for (int j = 0; j < 4; ++j) {
        int row = r0 + wm * 64 + mf * 16 + lg * 4 + j;
        out[(size_t)row * 256 + col] = acc[mf][nf][j];
      }
    }
}

// ---------------------------------------------------------------------------
extern "C" void kernel_launch(void* const* d_in, const int* in_sizes, int n_in,
                              void* d_out, int out_size, void* d_ws,
                              size_t ws_size, hipStream_t stream) {
  const float* msa  = (const float*)d_in[0];
  const float* pair = (const float*)d_in[1];
  const float* Wg   = (const float*)d_in[2];
  const float* Wqkv = (const float*)d_in[3];
  const float* Wout = (const float*)d_in[4];
  const float* Bp   = (const float*)d_in[5];
  float* out = (float*)d_out;
  short* sw = (short*)d_ws;

  short* bias_bf = sw;                 //   524288 shorts
  short* gate_bf = sw + 524288;        //  8388608
  short* qkv_bf  = sw + 8912896;       // 25165824
  short* attn_bf = sw + 34078720;      //  8388608
  short* Wt_bf   = sw + 42467328;      //   262144
  short* Woutt   = sw + 42729472;      //    65536
  short* X_bf    = sw + 42795008;      //  8388608
  float* bprojT  = (float*)(sw + 51183616);  // 1024 f32

  hipLaunchKernelGGL(wconv_kernel, dim3(1284), dim3(256), 0, stream,
                     Wg, Wqkv, Wout, Bp, Wt_bf, Woutt, bprojT);
  hipLaunchKernelGGL(xconv_kernel, dim3(4096), dim3(256), 0, stream,
                     msa, X_bf);
  hipLaunchKernelGGL(bias2_kernel, dim3(512), dim3(256), 0, stream,
                     pair, bprojT, bias_bf);
  hipLaunchKernelGGL(gemm_fused3, dim3(2048), dim3(256), 0, stream,
                     X_bf, Wt_bf, gate_bf, qkv_bf);
  hipLaunchKernelGGL(attn_mfma4, dim3(128, 8), dim3(512), 0, stream,
                     qkv_bf, bias_bf, gate_bf, attn_bf);
  hipLaunchKernelGGL(gemm_out2, dim3(256, 2), dim3(256), 0, stream,
                     attn_bf, Woutt, out);
}

// Round 14
// 97.480 us; speedup vs baseline: 1.1272x; 1.0466x over previous
//
#include <hip/hip_runtime.h>
#include <hip/hip_bf16.h>
#include <math.h>

typedef __attribute__((ext_vector_type(8))) short bf16x8;
typedef __attribute__((ext_vector_type(4))) short bf16x4;
typedef __attribute__((ext_vector_type(4))) float f32x4;

#define MFMA32 __builtin_amdgcn_mfma_f32_16x16x32_bf16
#define MFMA16 __builtin_amdgcn_mfma_f32_16x16x16bf16_1k

#define QSCALE 0.25503485964546277f  // (1/sqrt(32)) * log2(e)

__device__ inline short bfbits(float f) {
  union { float f; unsigned u; } v; v.f = f;
  unsigned r = v.u + 0x7fffu + ((v.u >> 16) & 1u);
  return (short)(r >> 16);
}
__device__ inline float bf2f(unsigned short u) {
  union { unsigned u; float f; } v; v.u = ((unsigned)u) << 16; return v.f;
}
__device__ inline void gll16(const void* g, void* l) {
  __builtin_amdgcn_global_load_lds(
      (const __attribute__((address_space(1))) unsigned*)g,
      (__attribute__((address_space(3))) unsigned*)l, 16, 0, 0);
}
// pack 4 f32 -> bf16x4 via v_cvt_pk_bf16_f32 (RTNE)
__device__ inline bf16x4 pk4(float e0, float e1, float e2, float e3) {
  unsigned lo, hi;
  asm("v_cvt_pk_bf16_f32 %0, %1, %2" : "=v"(lo) : "v"(e0), "v"(e1));
  asm("v_cvt_pk_bf16_f32 %0, %1, %2" : "=v"(hi) : "v"(e2), "v"(e3));
  union { unsigned u[2]; bf16x4 v; } cv;
  cv.u[0] = lo; cv.u[1] = hi;
  return cv.v;
}

// ---------------------------------------------------------------------------
// prep2: ONE launch, three jobs. Block ranges EXACT (round-13 bug: wconv
// overflowed Woutt into X_bf -> dispatch-order nondeterminism).
//   bid [0,512)      : bias_bf[h][row] = bf16(sum_z pair[row,z]*bproj[z,h])
//   bid [512,1792)   : Wt (262144 = 1024 blk) + Woutt (65536 = 256 blk), exact
//   bid [1792,5888)  : X f32 -> Xbf bf16
// ---------------------------------------------------------------------------
__global__ __launch_bounds__(256) void prep2_kernel(
    const float* __restrict__ X, const float* __restrict__ pair,
    const float* __restrict__ bproj, const float* __restrict__ Wg,
    const float* __restrict__ Wqkv, const float* __restrict__ Wout,
    short* __restrict__ Xbf, short* __restrict__ bias_bf,
    short* __restrict__ Wt, short* __restrict__ Woutt) {
  __shared__ float bp[1024];      // bp[h*128+z] = bproj[z*8+h]
  __shared__ float red[128][8];
  int bid = blockIdx.x;
  int t = threadIdx.x;
  if (bid < 512) {  // ---- bias ----
    for (int i = t; i < 1024; i += 256)
      bp[i] = bproj[(i & 127) * 8 + (i >> 7)];
    __syncthreads();
    int row = bid * 128 + (t & 127);
    int zh = t >> 7;  // wave-uniform z-half
    const float4* src = (const float4*)(pair + (size_t)row * 128 + zh * 64);
    float acc[8] = {};
#pragma unroll
    for (int z4 = 0; z4 < 16; ++z4) {
      float4 v = src[z4];
#pragma unroll
      for (int h = 0; h < 8; ++h) {
        float4 b = *(const float4*)&bp[h * 128 + zh * 64 + z4 * 4];  // bcast
        acc[h] += v.x * b.x + v.y * b.y + v.z * b.z + v.w * b.w;
      }
    }
    if (t >= 128) {
#pragma unroll
      for (int h = 0; h < 8; ++h) red[t - 128][h] = acc[h];
    }
    __syncthreads();
    if (t < 128) {
#pragma unroll
      for (int h = 0; h < 8; ++h)
        bias_bf[(size_t)h * 65536 + row] = bfbits(acc[h] + red[t][h]);
    }
  } else if (bid < 1792) {  // ---- wconv (exact: 1280 blocks) ----
    int idx = (bid - 512) * 256 + t;  // [0, 327680)
    if (idx < 1024 * 256) {
      int col = idx >> 8, k = idx & 255;
      float v;
      if (col < 256) {
        v = Wg[k * 256 + col];
      } else {
        int wc = col - 256;
        v = Wqkv[k * 768 + wc];
        if ((wc % 96) < 32) v *= QSCALE;
      }
      Wt[idx] = bfbits(v);
    } else {
      int j = idx - 1024 * 256;  // [0, 65536) exact
      int col = j >> 8, k = j & 255;
      Woutt[j] = bfbits(Wout[k * 256 + col]);
    }
  } else {  // ---- xconv (4096 blocks) ----
    size_t i = ((size_t)(bid - 1792) * 256 + t) * 8;
    float4 a = *(const float4*)(X + i);
    float4 b = *(const float4*)(X + i + 4);
    bf16x8 o = {bfbits(a.x), bfbits(a.y), bfbits(a.z), bfbits(a.w),
                bfbits(b.x), bfbits(b.y), bfbits(b.z), bfbits(b.w)};
    *(bf16x8*)(Xbf + i) = o;
  }
}

// ---------------------------------------------------------------------------
// gemm_fused3: Xbf[32768,256]bf16 @ Wt^T -> gate(sigmoid,bf16) | qkv(bf16)
// 2048 blocks (XCD-chunked, ny fastest), 256 thr, tile 128x128, BK=32,
// both operands double-buffered via global_load_lds (swizzled). LDS 32KB.
// ---------------------------------------------------------------------------
__global__ __launch_bounds__(256) void gemm_fused3(
    const short* __restrict__ Xbf, const short* __restrict__ Wt,
    short* __restrict__ gate_bf, short* __restrict__ qkv_bf) {
  __shared__ short As[2][128 * 32];  // 2 x 8KB
  __shared__ short Bs[2][128 * 32];  // 2 x 8KB
  int t = threadIdx.x;
  int lane = t & 63, wid = t >> 6;
  int lq = lane & 15, lg = lane >> 4;
  int wm = wid >> 1, wn = wid & 1;

  int flat = blockIdx.x;
  int xcd = flat & 7, local = flat >> 3;
  int ny = local & 7;
  int bx = xcd * 32 + (local >> 3);
  int r0 = bx * 128;
  int cW = ny * 128;

  auto stageA = [&](int kq, int buf) {
#pragma unroll
    for (int c = 0; c < 2; ++c) {
      int D = c * 4096 + t * 16;
      int row = D >> 6;
      int sl = ((D >> 4) & 3) ^ ((row >> 1) & 3);
      gll16(Xbf + (size_t)(r0 + row) * 256 + kq * 32 + sl * 8,
            (char*)&As[buf][0] + D);
    }
  };
  auto stageB = [&](int kq, int buf) {
#pragma unroll
    for (int c = 0; c < 2; ++c) {
      int D = c * 4096 + t * 16;
      int col = D >> 6;
      int sl = ((D >> 4) & 3) ^ ((col >> 1) & 3);
      gll16(Wt + (size_t)(cW + col) * 256 + kq * 32 + sl * 8,
            (char*)&Bs[buf][0] + D);
    }
  };

  f32x4 acc[4][4];
#pragma unroll
  for (int a = 0; a < 4; ++a)
#pragma unroll
    for (int b = 0; b < 4; ++b) acc[a][b] = {0.f, 0.f, 0.f, 0.f};

  stageA(0, 0);
  stageB(0, 0);
  __syncthreads();

  for (int kq = 0; kq < 8; ++kq) {
    int buf = kq & 1;
    if (kq < 7) {
      stageA(kq + 1, buf ^ 1);
      stageB(kq + 1, buf ^ 1);
    }
    bf16x8 afr[4], bfr[4];
#pragma unroll
    for (int mf = 0; mf < 4; ++mf) {
      int row = wm * 64 + mf * 16 + lq;
      int sl = lg ^ ((row >> 1) & 3);
      afr[mf] = *(const bf16x8*)((const char*)&As[buf][0] + row * 64 + sl * 16);
    }
#pragma unroll
    for (int nf = 0; nf < 4; ++nf) {
      int col = wn * 64 + nf * 16 + lq;
      int sl = lg ^ ((col >> 1) & 3);
      bfr[nf] = *(const bf16x8*)((const char*)&Bs[buf][0] + col * 64 + sl * 16);
    }
#pragma unroll
    for (int mf = 0; mf < 4; ++mf)
#pragma unroll
      for (int nf = 0; nf < 4; ++nf)
        acc[mf][nf] = MFMA32(afr[mf], bfr[nf], acc[mf][nf], 0, 0, 0);
    __syncthreads();
  }

  if (cW < 256) {
#pragma unroll
    for (int mf = 0; mf < 4; ++mf)
#pragma unroll
      for (int nf = 0; nf < 4; ++nf) {
        int col = cW + wn * 64 + nf * 16 + lq;
#pragma unroll
        for (int j = 0; j < 4; ++j) {
          int row = r0 + wm * 64 + mf * 16 + lg * 4 + j;
          float v = acc[mf][nf][j];
          float sg = __builtin_amdgcn_rcpf(1.f + __expf(-v));
          gate_bf[(size_t)row * 256 + col] = bfbits(sg);
        }
      }
  } else {
    int cb = cW - 256;
#pragma unroll
    for (int mf = 0; mf < 4; ++mf)
#pragma unroll
      for (int nf = 0; nf < 4; ++nf) {
        int col = cb + wn * 64 + nf * 16 + lq;
#pragma unroll
        for (int j = 0; j < 4; ++j) {
          int row = r0 + wm * 64 + mf * 16 + lg * 4 + j;
          qkv_bf[(size_t)row * 768 + col] = bfbits(acc[mf][nf][j]);
        }
      }
  }
}

// ---------------------------------------------------------------------------
// attn v5: z-split. Grid (128 s, 8 h, 2 z), 256 thr (4 waves x 32 rows).
// K in LDS (gll16, slot-swizzled, full 256p); V^T in LDS; BV via MFMA32;
// E=exp2(K@Q^T) -> pk4; attend = (E@V)*rcp(E@1) + bias@V; LDS-bounce epilogue.
// ---------------------------------------------------------------------------
__global__ __launch_bounds__(256, 4) void attn_mfma5(
    const short* __restrict__ qkv, const short* __restrict__ bias_bf,
    const short* __restrict__ gate_bf, short* __restrict__ attn_bf) {
  int s = blockIdx.x, h = blockIdx.y, z = blockIdx.z;
  __shared__ short Ks[8192];       // 16KB: [256 p][4 slots 16B] slot-swizzled
  __shared__ short Vt[32][260];    // 16.6KB
  short* Res = Ks;                 // reused after PV (barrier-protected)
  int t = threadIdx.x;
  int lane = t & 63, wid = t >> 6;
  int lq = lane & 15, lg = lane >> 4;
  const short* qkv_s = qkv + (size_t)s * 196608 + h * 96;

  // stage K (full 256 p): linear LDS dest, pre-swizzled source
#pragma unroll
  for (int q = 0; q < 4; ++q) {
    int off = q * 4096 + t * 16;
    int p = off >> 6;
    int slot = (off >> 4) & 3;
    int cg = slot ^ ((p >> 1) & 3);
    gll16(qkv_s + p * 768 + 32 + cg * 8, (char*)Ks + off);
  }
  // stage V^T (register transpose): thread t owns p=t, all 32 c
  {
    const short* src = qkv_s + (size_t)t * 768 + 64;
    bf16x8 v0 = *(const bf16x8*)src;
    bf16x8 v1 = *(const bf16x8*)(src + 8);
    bf16x8 v2 = *(const bf16x8*)(src + 16);
    bf16x8 v3 = *(const bf16x8*)(src + 24);
#pragma unroll
    for (int i = 0; i < 8; ++i) {
      Vt[i][t] = v0[i];      Vt[8 + i][t] = v1[i];
      Vt[16 + i][t] = v2[i]; Vt[24 + i][t] = v3[i];
    }
  }

  int rbase = z * 128 + wid * 32;
  bf16x8 qf0 = *(const bf16x8*)(qkv_s + (size_t)(rbase + lq) * 768 + lg * 8);
  bf16x8 qf1 = *(const bf16x8*)(qkv_s + (size_t)(rbase + 16 + lq) * 768 + lg * 8);
  const short* bb0 =
      bias_bf + ((size_t)h * 256 + rbase + lq) * 256 + lg * 8;  // 16B frags
  const short* bb1 = bb0 + 16 * 256;

  f32x4 U[2][2], BV[2][2], L[2];
#pragma unroll
  for (int ri = 0; ri < 2; ++ri) {
    L[ri] = {0.f, 0.f, 0.f, 0.f};
#pragma unroll
    for (int ct = 0; ct < 2; ++ct) {
      U[ri][ct] = {0.f, 0.f, 0.f, 0.f};
      BV[ri][ct] = {0.f, 0.f, 0.f, 0.f};
    }
  }
  const bf16x4 ones = {16256, 16256, 16256, 16256};  // bf16 1.0

  __syncthreads();

#pragma unroll
  for (int qtr = 0; qtr < 4; ++qtr) {
    bf16x8 kf[4];
    bf16x8 bfa[2][2];
#pragma unroll
    for (int i = 0; i < 4; ++i) {
      int row = (qtr * 4 + i) * 16 + lq;
      kf[i] = *(const bf16x8*)((const char*)Ks + row * 64 +
                               ((lg ^ ((row >> 1) & 3)) << 4));
    }
#pragma unroll
    for (int c2 = 0; c2 < 2; ++c2) {
      int chunk = qtr * 2 + c2;
      bfa[c2][0] = *(const bf16x8*)(bb0 + chunk * 32);
      bfa[c2][1] = *(const bf16x8*)(bb1 + chunk * 32);
    }

    f32x4 acc[2][4];
#pragma unroll
    for (int ri = 0; ri < 2; ++ri)
#pragma unroll
      for (int i = 0; i < 4; ++i) acc[ri][i] = {0.f, 0.f, 0.f, 0.f};
    __builtin_amdgcn_s_setprio(1);
#pragma unroll
    for (int i = 0; i < 4; ++i) {
      acc[0][i] = MFMA32(kf[i], qf0, acc[0][i], 0, 0, 0);
      acc[1][i] = MFMA32(kf[i], qf1, acc[1][i], 0, 0, 0);
    }
#pragma unroll
    for (int c2 = 0; c2 < 2; ++c2) {
      int chunk = qtr * 2 + c2;
      bf16x8 v0 = *(const bf16x8*)&Vt[lq][chunk * 32 + lg * 8];
      bf16x8 v1 = *(const bf16x8*)&Vt[16 + lq][chunk * 32 + lg * 8];
      BV[0][0] = MFMA32(bfa[c2][0], v0, BV[0][0], 0, 0, 0);
      BV[0][1] = MFMA32(bfa[c2][0], v1, BV[0][1], 0, 0, 0);
      BV[1][0] = MFMA32(bfa[c2][1], v0, BV[1][0], 0, 0, 0);
      BV[1][1] = MFMA32(bfa[c2][1], v1, BV[1][1], 0, 0, 0);
    }
    __builtin_amdgcn_s_setprio(0);

    bf16x4 af[2][4];
#pragma unroll
    for (int ri = 0; ri < 2; ++ri)
#pragma unroll
      for (int i = 0; i < 4; ++i)
        af[ri][i] = pk4(__builtin_amdgcn_exp2f(acc[ri][i][0]),
                        __builtin_amdgcn_exp2f(acc[ri][i][1]),
                        __builtin_amdgcn_exp2f(acc[ri][i][2]),
                        __builtin_amdgcn_exp2f(acc[ri][i][3]));

    __builtin_amdgcn_s_setprio(1);
#pragma unroll
    for (int i = 0; i < 4; ++i) {
      int kc = qtr * 4 + i;
      bf16x4 vf0 = *(const bf16x4*)&Vt[lq][kc * 16 + lg * 4];
      bf16x4 vf1 = *(const bf16x4*)&Vt[16 + lq][kc * 16 + lg * 4];
#pragma unroll
      for (int ri = 0; ri < 2; ++ri) {
        U[ri][0] = MFMA16(af[ri][i], vf0, U[ri][0], 0, 0, 0);
        U[ri][1] = MFMA16(af[ri][i], vf1, U[ri][1], 0, 0, 0);
        L[ri]    = MFMA16(af[ri][i], ones, L[ri], 0, 0, 0);
      }
    }
    __builtin_amdgcn_s_setprio(0);
  }

  __syncthreads();  // done reading Ks/Vt; reuse Ks as Res (128 rows x 32)

#pragma unroll
  for (int ri = 0; ri < 2; ++ri) {
    f32x4 inv;
#pragma unroll
    for (int j = 0; j < 4; ++j) inv[j] = __builtin_amdgcn_rcpf(L[ri][j]);
#pragma unroll
    for (int ct = 0; ct < 2; ++ct) {
#pragma unroll
      for (int j = 0; j < 4; ++j) {
        int rl = wid * 32 + ri * 16 + lg * 4 + j;  // local row 0..127
        Res[rl * 32 + ct * 16 + lq] =
            bfbits(U[ri][ct][j] * inv[j] + BV[ri][ct][j]);
      }
    }
  }
  __syncthreads();

  // coalesced epilogue: gate multiply + 16B stores (128 rows x 2 halves)
  {
    int row = t & 127, hf = t >> 7;
    size_t o = ((size_t)(s * 256 + z * 128 + row)) * 256 + h * 32 + hf * 16;
    bf16x8 r0 = *(const bf16x8*)&Res[row * 32 + hf * 16];
    bf16x8 r1 = *(const bf16x8*)&Res[row * 32 + hf * 16 + 8];
    bf16x8 g0 = *(const bf16x8*)&gate_bf[o];
    bf16x8 g1 = *(const bf16x8*)&gate_bf[o + 8];
    bf16x8 o0, o1;
#pragma unroll
    for (int i = 0; i < 8; ++i) {
      o0[i] = bfbits(bf2f((unsigned short)r0[i]) * bf2f((unsigned short)g0[i]));
      o1[i] = bfbits(bf2f((unsigned short)r1[i]) * bf2f((unsigned short)g1[i]));
    }
    *(bf16x8*)&attn_bf[o] = o0;
    *(bf16x8*)&attn_bf[o + 8] = o1;
  }
}

// ---------------------------------------------------------------------------
// gemm_out: attn_bf[32768,256] @ Woutt^T -> out f32
// ---------------------------------------------------------------------------
__global__ __launch_bounds__(256) void gemm_out2(
    const short* __restrict__ A, const short* __restrict__ Wt,
    float* __restrict__ out) {
  __shared__ short As2[2][128 * 64];
  __shared__ short Bs2[2][128 * 64];
  int t = threadIdx.x;
  int lane = t & 63, wid = t >> 6;
  int lq = lane & 15, lg = lane >> 4;
  int wm = wid >> 1, wn = wid & 1;
  int r0 = blockIdx.x * 128, n0 = blockIdx.y * 128;

  auto stage = [&](int s, int buf) {
#pragma unroll
    for (int q = 0; q < 4; ++q) {
      int P = wid * 4096 + q * 1024 + lane * 16;
      int row = P >> 7, kb = P & 127;
      int klog = kb ^ ((row & 7) << 4);
      gll16((const char*)A + ((size_t)(r0 + row) * 512 + s * 128 + klog),
            (char*)&As2[buf][0] + wid * 4096 + q * 1024);
      gll16((const char*)Wt + ((size_t)(n0 + row) * 512 + s * 128 + klog),
            (char*)&Bs2[buf][0] + wid * 4096 + q * 1024);
    }
  };

  f32x4 acc[4][4];
#pragma unroll
  for (int a = 0; a < 4; ++a)
#pragma unroll
    for (int b = 0; b < 4; ++b) acc[a][b] = {0.f, 0.f, 0.f, 0.f};

  stage(0, 0);
  __syncthreads();
  for (int s = 0; s < 4; ++s) {
    if (s < 3) stage(s + 1, (s + 1) & 1);
    bf16x8 afr[4][2], bfr[4][2];
#pragma unroll
    for (int kcl = 0; kcl < 2; ++kcl) {
#pragma unroll
      for (int mf = 0; mf < 4; ++mf) {
        int row = wm * 64 + mf * 16 + lq;
        int kb = (((kcl << 6) | (lg << 4))) ^ ((row & 7) << 4);
        afr[mf][kcl] = *(const bf16x8*)((const char*)&As2[s & 1][0] + row * 128 + kb);
      }
#pragma unroll
      for (int nf = 0; nf < 4; ++nf) {
        int col = wn * 64 + nf * 16 + lq;
        int kb = (((kcl << 6) | (lg << 4))) ^ ((col & 7) << 4);
        bfr[nf][kcl] = *(const bf16x8*)((const char*)&Bs2[s & 1][0] + col * 128 + kb);
      }
    }
#pragma unroll
    for (int mf = 0; mf < 4; ++mf)
#pragma unroll
      for (int nf = 0; nf < 4; ++nf)
#pragma unroll
        for (int kcl = 0; kcl < 2; ++kcl)
          acc[mf][nf] = MFMA32(afr[mf][kcl], bfr[nf][kcl], acc[mf][nf], 0, 0, 0);
    __syncthreads();
  }
#pragma unroll
  for (int mf = 0; mf < 4; ++mf)
#pragma unroll
    for (int nf = 0; nf < 4; ++nf) {
      int col = n0 + wn * 64 + nf * 16 + lq;
#pragma unroll
      for (int j = 0; j < 4; ++j) {
        int row = r0 + wm * 64 + mf * 16 + lg * 4 + j;
        out[(size_t)row * 256 + col] = acc[mf][nf][j];
      }
    }
}

// ---------------------------------------------------------------------------
extern "C" void kernel_launch(void* const* d_in, const int* in_sizes, int n_in,
                              void* d_out, int out_size, void* d_ws,
                              size_t ws_size, hipStream_t stream) {
  const float* msa  = (const float*)d_in[0];
  const float* pair = (const float*)d_in[1];
  const float* Wg   = (const float*)d_in[2];
  const float* Wqkv = (const float*)d_in[3];
  const float* Wout = (const float*)d_in[4];
  const float* Bp   = (const float*)d_in[5];
  float* out = (float*)d_out;
  short* sw = (short*)d_ws;

  short* bias_bf = sw;                 //   524288 shorts
  short* gate_bf = sw + 524288;        //  8388608
  short* qkv_bf  = sw + 8912896;       // 25165824
  short* attn_bf = sw + 34078720;      //  8388608
  short* Wt_bf   = sw + 42467328;      //   262144
  short* Woutt   = sw + 42729472;      //    65536
  short* X_bf    = sw + 42795008;      //  8388608

  hipLaunchKernelGGL(prep2_kernel, dim3(5888), dim3(256), 0, stream,
                     msa, pair, Bp, Wg, Wqkv, Wout,
                     X_bf, bias_bf, Wt_bf, Woutt);
  hipLaunchKernelGGL(gemm_fused3, dim3(2048), dim3(256), 0, stream,
                     X_bf, Wt_bf, gate_bf, qkv_bf);
  hipLaunchKernelGGL(attn_mfma5, dim3(128, 8, 2), dim3(256), 0, stream,
                     qkv_bf, bias_bf, gate_bf, attn_bf);
  hipLaunchKernelGGL(gemm_out2, dim3(256, 2), dim3(256), 0, stream,
                     attn_bf, Woutt, out);
}

// Round 15
// 76.571 us; speedup vs baseline: 1.4350x; 1.2731x over previous
//
#include <hip/hip_runtime.h>
#include <hip/hip_bf16.h>
#include <math.h>

typedef __attribute__((ext_vector_type(8))) short bf16x8;
typedef __attribute__((ext_vector_type(4))) short bf16x4;
typedef __attribute__((ext_vector_type(4))) float f32x4;

#define MFMA32 __builtin_amdgcn_mfma_f32_16x16x32_bf16
#define MFMA16 __builtin_amdgcn_mfma_f32_16x16x16bf16_1k

#define QSCALE 0.25503485964546277f  // (1/sqrt(32)) * log2(e)

__device__ inline short bfbits(float f) {
  union { float f; unsigned u; } v; v.f = f;
  unsigned r = v.u + 0x7fffu + ((v.u >> 16) & 1u);
  return (short)(r >> 16);
}
__device__ inline float bf2f(unsigned short u) {
  union { unsigned u; float f; } v; v.u = ((unsigned)u) << 16; return v.f;
}
__device__ inline void gll16(const void* g, void* l) {
  __builtin_amdgcn_global_load_lds(
      (const __attribute__((address_space(1))) unsigned*)g,
      (__attribute__((address_space(3))) unsigned*)l, 16, 0, 0);
}
// pack 4 f32 -> bf16x4 via v_cvt_pk_bf16_f32 (RTNE)
__device__ inline bf16x4 pk4(float e0, float e1, float e2, float e3) {
  unsigned lo, hi;
  asm("v_cvt_pk_bf16_f32 %0, %1, %2" : "=v"(lo) : "v"(e0), "v"(e1));
  asm("v_cvt_pk_bf16_f32 %0, %1, %2" : "=v"(hi) : "v"(e2), "v"(e3));
  union { unsigned u[2]; bf16x4 v; } cv;
  cv.u[0] = lo; cv.u[1] = hi;
  return cv.v;
}

// ---------------------------------------------------------------------------
// prep2: ONE launch, three jobs, exact block ranges.
//   bid [0,512)      : bias_bf[h][row] = bf16(sum_z pair[row,z]*bproj[z,h])
//   bid [512,1792)   : Wh[h][c][k] (q|k|v|gate per head, q prescaled) 1024 blk
//                      + Woutt[col][k] 256 blk (exact)
//   bid [1792,5888)  : X f32 -> Xbf bf16
// ---------------------------------------------------------------------------
__global__ __launch_bounds__(256) void prep2_kernel(
    const float* __restrict__ X, const float* __restrict__ pair,
    const float* __restrict__ bproj, const float* __restrict__ Wg,
    const float* __restrict__ Wqkv, const float* __restrict__ Wout,
    short* __restrict__ Xbf, short* __restrict__ bias_bf,
    short* __restrict__ Wh, short* __restrict__ Woutt) {
  __shared__ float bp[1024];      // bp[h*128+z] = bproj[z*8+h]
  __shared__ float red[128][8];
  int bid = blockIdx.x;
  int t = threadIdx.x;
  if (bid < 512) {  // ---- bias ----
    for (int i = t; i < 1024; i += 256)
      bp[i] = bproj[(i & 127) * 8 + (i >> 7)];
    __syncthreads();
    int row = bid * 128 + (t & 127);
    int zh = t >> 7;  // wave-uniform z-half
    const float4* src = (const float4*)(pair + (size_t)row * 128 + zh * 64);
    float acc[8] = {};
#pragma unroll
    for (int z4 = 0; z4 < 16; ++z4) {
      float4 v = src[z4];
#pragma unroll
      for (int h = 0; h < 8; ++h) {
        float4 b = *(const float4*)&bp[h * 128 + zh * 64 + z4 * 4];  // bcast
        acc[h] += v.x * b.x + v.y * b.y + v.z * b.z + v.w * b.w;
      }
    }
    if (t >= 128) {
#pragma unroll
      for (int h = 0; h < 8; ++h) red[t - 128][h] = acc[h];
    }
    __syncthreads();
    if (t < 128) {
#pragma unroll
      for (int h = 0; h < 8; ++h)
        bias_bf[(size_t)h * 65536 + row] = bfbits(acc[h] + red[t][h]);
    }
  } else if (bid < 1792) {  // ---- Wh + Woutt (exact 1280 blocks) ----
    int idx = (bid - 512) * 256 + t;  // [0, 327680)
    if (idx < 262144) {
      // Wh[h][c][k]: c<32 q (x QSCALE) | 32-63 k | 64-95 v | 96-127 gate
      int h = idx >> 15, rem = idx & 32767;
      int c = rem >> 8, k = rem & 255;
      float v;
      if (c < 96) {
        v = Wqkv[k * 768 + h * 96 + c];
        if (c < 32) v *= QSCALE;
      } else {
        v = Wg[k * 256 + h * 32 + (c - 96)];
      }
      Wh[idx] = bfbits(v);
    } else {
      int j = idx - 262144;  // [0, 65536) exact
      int col = j >> 8, k = j & 255;
      Woutt[j] = bfbits(Wout[k * 256 + col]);
    }
  } else {  // ---- xconv (4096 blocks) ----
    size_t i = ((size_t)(bid - 1792) * 256 + t) * 8;
    float4 a = *(const float4*)(X + i);
    float4 b = *(const float4*)(X + i + 4);
    bf16x8 o = {bfbits(a.x), bfbits(a.y), bfbits(a.z), bfbits(a.w),
                bfbits(b.x), bfbits(b.y), bfbits(b.z), bfbits(b.w)};
    *(bf16x8*)(Xbf + i) = o;
  }
}

// ---------------------------------------------------------------------------
// fused_qkvattn: per (s,h) block (1024 blocks, 512 thr = 8 waves).
// Phase 1: GEMM Xbf[s-block 256x256] @ Wh[h]^T -> 256x128 (q|k|v|gate) in acc.
// Phase 2: scatter acc -> LDS: K,Q slot-swizzled [256][32]; V,gate [c][p].
// Phase 3: attn (= attn_mfma5): simT=K@Q^T, E=exp2, U=E@V, L=E@1, BV=bias@V,
//          out=(U*rcp(L)+BV)*gate; LDS-bounce coalesced store.
// qkv/gate NEVER touch global memory.
// ---------------------------------------------------------------------------
__global__ __launch_bounds__(512, 4) void fused_qkvattn(
    const short* __restrict__ Xbf, const short* __restrict__ Wh,
    const short* __restrict__ bias_bf, short* __restrict__ attn_bf) {
  // LDS (shorts): GEMM: A dbuf [0,16384) 2x8192, B dbuf [16384,24576) 2x4096.
  // Post-GEMM:  Ks [0,8192) | Qs [8192,16384) | Vt [16384,24704) [32][260]
  //             Gs [24704,33024) [32][260].  Res reuses Ks.
  __shared__ short lds[33024];
  int t = threadIdx.x;
  int lane = t & 63, wid = t >> 6;
  int lq = lane & 15, lg = lane >> 4;
  int flat = blockIdx.x;
  int xcd = flat & 7, local = flat >> 3;
  int h = local & 7;
  int s = xcd * 16 + (local >> 3);  // same-s blocks land on one XCD

  const short* xrow0 = Xbf + (size_t)s * 65536;  // 256 rows x 256 k
  const short* whh = Wh + h * 32768;             // 128 cols x 256 k

  // ================= Phase 1: GEMM =================
  int wm = wid >> 1, wn = wid & 1;  // 4 m-tiles x 2 n-tiles of 64
  auto stageA = [&](int kq, int buf) {
#pragma unroll
    for (int c = 0; c < 2; ++c) {
      int D = c * 8192 + t * 16;  // byte offset in A-buf (16KB)
      int row = D >> 6;
      int sl = ((D >> 4) & 3) ^ ((row >> 1) & 3);
      gll16(xrow0 + (size_t)row * 256 + kq * 32 + sl * 8,
            (char*)lds + buf * 16384 + D);
    }
  };
  auto stageB = [&](int kq, int buf) {
    int D = t * 16;  // byte offset in B-buf (8KB)
    int col = D >> 6;
    int sl = ((D >> 4) & 3) ^ ((col >> 1) & 3);
    gll16(whh + (size_t)col * 256 + kq * 32 + sl * 8,
          (char*)lds + 32768 + buf * 8192 + D);
  };

  f32x4 acc[4][4];
#pragma unroll
  for (int a = 0; a < 4; ++a)
#pragma unroll
    for (int b = 0; b < 4; ++b) acc[a][b] = {0.f, 0.f, 0.f, 0.f};

  stageA(0, 0);
  stageB(0, 0);
  __syncthreads();

  for (int kq = 0; kq < 8; ++kq) {
    int buf = kq & 1;
    if (kq < 7) {
      stageA(kq + 1, buf ^ 1);
      stageB(kq + 1, buf ^ 1);
    }
    bf16x8 afr[4], bfr[4];
#pragma unroll
    for (int mf = 0; mf < 4; ++mf) {
      int row = wm * 64 + mf * 16 + lq;
      int sl = lg ^ ((row >> 1) & 3);
      afr[mf] = *(const bf16x8*)((const char*)lds + buf * 16384 + row * 64 +
                                 sl * 16);
    }
#pragma unroll
    for (int nf = 0; nf < 4; ++nf) {
      int col = wn * 64 + nf * 16 + lq;
      int sl = lg ^ ((col >> 1) & 3);
      bfr[nf] = *(const bf16x8*)((const char*)lds + 32768 + buf * 8192 +
                                 col * 64 + sl * 16);
    }
#pragma unroll
    for (int mf = 0; mf < 4; ++mf)
#pragma unroll
      for (int nf = 0; nf < 4; ++nf)
        acc[mf][nf] = MFMA32(afr[mf], bfr[nf], acc[mf][nf], 0, 0, 0);
    __syncthreads();
  }

  // ================= Phase 2: scatter to LDS =================
  short* Ks = lds;           // [256][32] slot-swizzled (k)
  short* Qs = lds + 8192;    // [256][32] slot-swizzled (q)
  short* Vt = lds + 16384;   // [32][260] V^T
  short* Gs = lds + 24704;   // [32][260] gate^T (sigmoid applied)
  if (wn == 0) {  // cols 0..63 = q | k  -> swizzled [R][32] scalar writes
#pragma unroll
    for (int mf = 0; mf < 4; ++mf)
#pragma unroll
      for (int nf = 0; nf < 4; ++nf) {
        int c = nf * 16 + lq;          // 0..63
        int cc = c & 31;
        char* base = (char*)lds + ((c < 32) ? 16384 : 0);  // q->Qs, k->Ks
#pragma unroll
        for (int j = 0; j < 4; ++j) {
          int R = wm * 64 + mf * 16 + lg * 4 + j;
          *(short*)(base + R * 64 + ((((cc >> 3) ^ ((R >> 1) & 3)) << 4)) +
                    (cc & 7) * 2) = bfbits(acc[mf][nf][j]);
        }
      }
  } else {  // cols 64..127 = v | gate -> [c][p] packed bf16x4 writes
#pragma unroll
    for (int mf = 0; mf < 4; ++mf)
#pragma unroll
      for (int nf = 0; nf < 4; ++nf) {
        int R0 = wm * 64 + mf * 16 + lg * 4;
        if (nf < 2) {
          int c = nf * 16 + lq;
          bf16x4 v4 = {bfbits(acc[mf][nf][0]), bfbits(acc[mf][nf][1]),
                       bfbits(acc[mf][nf][2]), bfbits(acc[mf][nf][3])};
          *(bf16x4*)&Vt[c * 260 + R0] = v4;
        } else {
          int c = (nf - 2) * 16 + lq;
          bf16x4 g4;
#pragma unroll
          for (int j = 0; j < 4; ++j)
            g4[j] = bfbits(
                __builtin_amdgcn_rcpf(1.f + __expf(-acc[mf][nf][j])));
          *(bf16x4*)&Gs[c * 260 + R0] = g4;
        }
      }
  }
  __syncthreads();

  // ================= Phase 3: attention =================
  int rbase = wid * 32;  // 8 waves x 32 rows = 256 rows
  int qrow0 = rbase + lq, qrow1 = rbase + 16 + lq;
  bf16x8 qf0 = *(const bf16x8*)((const char*)lds + 16384 + qrow0 * 64 +
                                ((lg ^ ((qrow0 >> 1) & 3)) << 4));
  bf16x8 qf1 = *(const bf16x8*)((const char*)lds + 16384 + qrow1 * 64 +
                                ((lg ^ ((qrow1 >> 1) & 3)) << 4));
  const short* bb0 =
      bias_bf + ((size_t)h * 256 + rbase + lq) * 256 + lg * 8;  // 16B frags
  const short* bb1 = bb0 + 16 * 256;

  f32x4 U[2][2], BV[2][2], L[2];
#pragma unroll
  for (int ri = 0; ri < 2; ++ri) {
    L[ri] = {0.f, 0.f, 0.f, 0.f};
#pragma unroll
    for (int ct = 0; ct < 2; ++ct) {
      U[ri][ct] = {0.f, 0.f, 0.f, 0.f};
      BV[ri][ct] = {0.f, 0.f, 0.f, 0.f};
    }
  }
  const bf16x4 ones = {16256, 16256, 16256, 16256};  // bf16 1.0

#pragma unroll
  for (int qtr = 0; qtr < 4; ++qtr) {
    f32x4 sim[2][4];
#pragma unroll
    for (int ri = 0; ri < 2; ++ri)
#pragma unroll
      for (int i = 0; i < 4; ++i) sim[ri][i] = {0.f, 0.f, 0.f, 0.f};
    __builtin_amdgcn_s_setprio(1);
#pragma unroll
    for (int i = 0; i < 4; ++i) {
      int row = (qtr * 4 + i) * 16 + lq;
      bf16x8 kf = *(const bf16x8*)((const char*)lds + row * 64 +
                                   ((lg ^ ((row >> 1) & 3)) << 4));
      sim[0][i] = MFMA32(kf, qf0, sim[0][i], 0, 0, 0);
      sim[1][i] = MFMA32(kf, qf1, sim[1][i], 0, 0, 0);
    }
#pragma unroll
    for (int c2 = 0; c2 < 2; ++c2) {
      int chunk = qtr * 2 + c2;
      bf16x8 b0 = *(const bf16x8*)(bb0 + chunk * 32);
      bf16x8 b1 = *(const bf16x8*)(bb1 + chunk * 32);
      bf16x8 v0 = *(const bf16x8*)&Vt[lq * 260 + chunk * 32 + lg * 8];
      bf16x8 v1 = *(const bf16x8*)&Vt[(16 + lq) * 260 + chunk * 32 + lg * 8];
      BV[0][0] = MFMA32(b0, v0, BV[0][0], 0, 0, 0);
      BV[0][1] = MFMA32(b0, v1, BV[0][1], 0, 0, 0);
      BV[1][0] = MFMA32(b1, v0, BV[1][0], 0, 0, 0);
      BV[1][1] = MFMA32(b1, v1, BV[1][1], 0, 0, 0);
    }
    __builtin_amdgcn_s_setprio(0);

    bf16x4 af[2][4];
#pragma unroll
    for (int ri = 0; ri < 2; ++ri)
#pragma unroll
      for (int i = 0; i < 4; ++i)
        af[ri][i] = pk4(__builtin_amdgcn_exp2f(sim[ri][i][0]),
                        __builtin_amdgcn_exp2f(sim[ri][i][1]),
                        __builtin_amdgcn_exp2f(sim[ri][i][2]),
                        __builtin_amdgcn_exp2f(sim[ri][i][3]));

    __builtin_amdgcn_s_setprio(1);
#pragma unroll
    for (int i = 0; i < 4; ++i) {
      int kc = qtr * 4 + i;
      bf16x4 vf0 = *(const bf16x4*)&Vt[lq * 260 + kc * 16 + lg * 4];
      bf16x4 vf1 = *(const bf16x4*)&Vt[(16 + lq) * 260 + kc * 16 + lg * 4];
#pragma unroll
      for (int ri = 0; ri < 2; ++ri) {
        U[ri][0] = MFMA16(af[ri][i], vf0, U[ri][0], 0, 0, 0);
        U[ri][1] = MFMA16(af[ri][i], vf1, U[ri][1], 0, 0, 0);
        L[ri]    = MFMA16(af[ri][i], ones, L[ri], 0, 0, 0);
      }
    }
    __builtin_amdgcn_s_setprio(0);
  }

  __syncthreads();  // done reading Ks/Qs; reuse Ks as Res [256][32]
  short* Res = Ks;

#pragma unroll
  for (int ri = 0; ri < 2; ++ri) {
    f32x4 inv;
#pragma unroll
    for (int j = 0; j < 4; ++j) inv[j] = __builtin_amdgcn_rcpf(L[ri][j]);
#pragma unroll
    for (int ct = 0; ct < 2; ++ct) {
      int c = ct * 16 + lq;
      bf16x4 g4 = *(const bf16x4*)&Gs[c * 260 + rbase + ri * 16 + lg * 4];
#pragma unroll
      for (int j = 0; j < 4; ++j) {
        int rl = rbase + ri * 16 + lg * 4 + j;
        Res[rl * 32 + c] =
            bfbits((U[ri][ct][j] * inv[j] + BV[ri][ct][j]) *
                   bf2f((unsigned short)g4[j]));
      }
    }
  }
  __syncthreads();

  // coalesced store: 512 thr, 32B each (256 rows x 64B)
  {
    int row = t >> 1, hf = t & 1;
    size_t o = ((size_t)(s * 256 + row)) * 256 + h * 32 + hf * 16;
    bf16x8 r0 = *(const bf16x8*)&Res[row * 32 + hf * 16];
    bf16x8 r1 = *(const bf16x8*)&Res[row * 32 + hf * 16 + 8];
    *(bf16x8*)&attn_bf[o] = r0;
    *(bf16x8*)&attn_bf[o + 8] = r1;
  }
}

// ---------------------------------------------------------------------------
// gemm_out: attn_bf[32768,256] @ Woutt^T -> out f32
// ---------------------------------------------------------------------------
__global__ __launch_bounds__(256) void gemm_out2(
    const short* __restrict__ A, const short* __restrict__ Wt,
    float* __restrict__ out) {
  __shared__ short As2[2][128 * 64];
  __shared__ short Bs2[2][128 * 64];
  int t = threadIdx.x;
  int lane = t & 63, wid = t >> 6;
  int lq = lane & 15, lg = lane >> 4;
  int wm = wid >> 1, wn = wid & 1;
  int r0 = blockIdx.x * 128, n0 = blockIdx.y * 128;

  auto stage = [&](int s, int buf) {
#pragma unroll
    for (int q = 0; q < 4; ++q) {
      int P = wid * 4096 + q * 1024 + lane * 16;
      int row = P >> 7, kb = P & 127;
      int klog = kb ^ ((row & 7) << 4);
      gll16((const char*)A + ((size_t)(r0 + row) * 512 + s * 128 + klog),
            (char*)&As2[buf][0] + wid * 4096 + q * 1024);
      gll16((const char*)Wt + ((size_t)(n0 + row) * 512 + s * 128 + klog),
            (char*)&Bs2[buf][0] + wid * 4096 + q * 1024);
    }
  };

  f32x4 acc[4][4];
#pragma unroll
  for (int a = 0; a < 4; ++a)
#pragma unroll
    for (int b = 0; b < 4; ++b) acc[a][b] = {0.f, 0.f, 0.f, 0.f};

  stage(0, 0);
  __syncthreads();
  for (int s = 0; s < 4; ++s) {
    if (s < 3) stage(s + 1, (s + 1) & 1);
    bf16x8 afr[4][2], bfr[4][2];
#pragma unroll
    for (int kcl = 0; kcl < 2; ++kcl) {
#pragma unroll
      for (int mf = 0; mf < 4; ++mf) {
        int row = wm * 64 + mf * 16 + lq;
        int kb = (((kcl << 6) | (lg << 4))) ^ ((row & 7) << 4);
        afr[mf][kcl] = *(const bf16x8*)((const char*)&As2[s & 1][0] + row * 128 + kb);
      }
#pragma unroll
      for (int nf = 0; nf < 4; ++nf) {
        int col = wn * 64 + nf * 16 + lq;
        int kb = (((kcl << 6) | (lg << 4))) ^ ((col & 7) << 4);
        bfr[nf][kcl] = *(const bf16x8*)((const char*)&Bs2[s & 1][0] + col * 128 + kb);
      }
    }
#pragma unroll
    for (int mf = 0; mf < 4; ++mf)
#pragma unroll
      for (int nf = 0; nf < 4; ++nf)
#pragma unroll
        for (int kcl = 0; kcl < 2; ++kcl)
          acc[mf][nf] = MFMA32(afr[mf][kcl], bfr[nf][kcl], acc[mf][nf], 0, 0, 0);
    __syncthreads();
  }
#pragma unroll
  for (int mf = 0; mf < 4; ++mf)
#pragma unroll
    for (int nf = 0; nf < 4; ++nf) {
      int col = n0 + wn * 64 + nf * 16 + lq;
#pragma unroll
      for (int j = 0; j < 4; ++j) {
        int row = r0 + wm * 64 + mf * 16 + lg * 4 + j;
        out[(size_t)row * 256 + col] = acc[mf][nf][j];
      }
    }
}

// ---------------------------------------------------------------------------
extern "C" void kernel_launch(void* const* d_in, const int* in_sizes, int n_in,
                              void* d_out, int out_size, void* d_ws,
                              size_t ws_size, hipStream_t stream) {
  const float* msa  = (const float*)d_in[0];
  const float* pair = (const float*)d_in[1];
  const float* Wg   = (const float*)d_in[2];
  const float* Wqkv = (const float*)d_in[3];
  const float* Wout = (const float*)d_in[4];
  const float* Bp   = (const float*)d_in[5];
  float* out = (float*)d_out;
  short* sw = (short*)d_ws;

  short* bias_bf = sw;                 //   524288 shorts
  short* attn_bf = sw + 524288;        //  8388608
  short* Wh_bf   = sw + 8912896;       //   262144
  short* Woutt   = sw + 9175040;       //    65536
  short* X_bf    = sw + 9240576;       //  8388608

  hipLaunchKernelGGL(prep2_kernel, dim3(5888), dim3(256), 0, stream,
                     msa, pair, Bp, Wg, Wqkv, Wout,
                     X_bf, bias_bf, Wh_bf, Woutt);
  hipLaunchKernelGGL(fused_qkvattn, dim3(1024), dim3(512), 0, stream,
                     X_bf, Wh_bf, bias_bf, attn_bf);
  hipLaunchKernelGGL(gemm_out2, dim3(256, 2), dim3(256), 0, stream,
                     attn_bf, Woutt, out);
}